// Round 2
// baseline (218.921 us; speedup 1.0000x reference)
//
#include <hip/hip_runtime.h>

static constexpr int BATCH = 65536;
static constexpr int DDIM  = 512;
static constexpr int NCLS  = 7;
static constexpr int GRID_MAIN = 2048;              // 2048 blk * 4 waves = 32 waves/CU
static constexpr int ROWS_PER_BLOCK = BATCH / GRID_MAIN;  // 32

struct WS {
  double sumsq;   // sum over all features^2
  double ce;      // sum of -logp[target]
  double l1;      // sum of |attention_weights|
  double pad;
  float  sums[NCLS * DDIM];  // per-class feature sums
  float  counts[NCLS];       // per-class counts
};

__device__ __forceinline__ float wave_reduce(float v) {
#pragma unroll
  for (int off = 32; off > 0; off >>= 1) v += __shfl_down(v, off);
  return v;
}

// Main streaming pass over features + attention_weights.
// Each block owns a contiguous 32-row chunk; 256 threads cover D=512 as float2.
// 4-row unroll: targets via one int4, 8 float2 loads issued up front (64B/thread
// in flight), branch-free predicated per-class accumulation (static indices ->
// registers, no scratch). Counts are NOT accumulated here (moved to k_ce).
__global__ __launch_bounds__(256, 8) void k_main(const float* __restrict__ features,
                                                 const int* __restrict__ targets,
                                                 const float* __restrict__ aw,
                                                 WS* __restrict__ ws) {
  const int tid = threadIdx.x;
  const float2* __restrict__ F = reinterpret_cast<const float2*>(features);
  const float2* __restrict__ A = reinterpret_cast<const float2*>(aw);

  float2 acc[NCLS];
#pragma unroll
  for (int c = 0; c < NCLS; ++c) acc[c] = make_float2(0.f, 0.f);
  float sumsq = 0.f, l1 = 0.f;

  const int base = blockIdx.x * ROWS_PER_BLOCK;
  for (int r = base; r < base + ROWS_PER_BLOCK; r += 4) {
    const int4 t4 = *reinterpret_cast<const int4*>(&targets[r]);
    const size_t idx = (size_t)r * (DDIM / 2) + tid;
    const float2 f0 = F[idx];
    const float2 f1 = F[idx + 1 * (DDIM / 2)];
    const float2 f2 = F[idx + 2 * (DDIM / 2)];
    const float2 f3 = F[idx + 3 * (DDIM / 2)];
    const float2 w0 = A[idx];
    const float2 w1 = A[idx + 1 * (DDIM / 2)];
    const float2 w2 = A[idx + 2 * (DDIM / 2)];
    const float2 w3 = A[idx + 3 * (DDIM / 2)];

    sumsq = fmaf(f0.x, f0.x, sumsq); sumsq = fmaf(f0.y, f0.y, sumsq);
    sumsq = fmaf(f1.x, f1.x, sumsq); sumsq = fmaf(f1.y, f1.y, sumsq);
    sumsq = fmaf(f2.x, f2.x, sumsq); sumsq = fmaf(f2.y, f2.y, sumsq);
    sumsq = fmaf(f3.x, f3.x, sumsq); sumsq = fmaf(f3.y, f3.y, sumsq);
    l1 += fabsf(w0.x) + fabsf(w0.y) + fabsf(w1.x) + fabsf(w1.y) +
          fabsf(w2.x) + fabsf(w2.y) + fabsf(w3.x) + fabsf(w3.y);

#pragma unroll
    for (int c = 0; c < NCLS; ++c) {
      acc[c].x += (t4.x == c) ? f0.x : 0.f;
      acc[c].y += (t4.x == c) ? f0.y : 0.f;
      acc[c].x += (t4.y == c) ? f1.x : 0.f;
      acc[c].y += (t4.y == c) ? f1.y : 0.f;
      acc[c].x += (t4.z == c) ? f2.x : 0.f;
      acc[c].y += (t4.z == c) ? f2.y : 0.f;
      acc[c].x += (t4.w == c) ? f3.x : 0.f;
      acc[c].y += (t4.w == c) ? f3.y : 0.f;
    }
  }

  // Merge per-class sums: thread owns cols {2*tid, 2*tid+1}.
  const int col = 2 * tid;
#pragma unroll
  for (int c = 0; c < NCLS; ++c) {
    atomicAdd(&ws->sums[c * DDIM + col],     acc[c].x);
    atomicAdd(&ws->sums[c * DDIM + col + 1], acc[c].y);
  }

  __shared__ float lds[4];
  const int lane = tid & 63, wid = tid >> 6;

  float bs = wave_reduce(sumsq);
  if (lane == 0) lds[wid] = bs;
  __syncthreads();
  if (tid == 0) atomicAdd(&ws->sumsq, (double)(lds[0] + lds[1] + lds[2] + lds[3]));
  __syncthreads();

  float bl = wave_reduce(l1);
  if (lane == 0) lds[wid] = bl;
  __syncthreads();
  if (tid == 0) atomicAdd(&ws->l1, (double)(lds[0] + lds[1] + lds[2] + lds[3]));
}

// Cross-entropy over [B, 7] logits (one row per thread) + per-class counts.
__global__ __launch_bounds__(256) void k_ce(const float* __restrict__ outputs,
                                            const int* __restrict__ targets,
                                            WS* __restrict__ ws) {
  float local = 0.f;
  float cnt[NCLS];
#pragma unroll
  for (int c = 0; c < NCLS; ++c) cnt[c] = 0.f;

  for (int row = blockIdx.x * blockDim.x + threadIdx.x; row < BATCH;
       row += gridDim.x * blockDim.x) {
    const float* o = outputs + row * NCLS;
    const float x0 = o[0], x1 = o[1], x2 = o[2], x3 = o[3], x4 = o[4], x5 = o[5], x6 = o[6];
    const float m = fmaxf(fmaxf(fmaxf(x0, x1), fmaxf(x2, x3)),
                          fmaxf(fmaxf(x4, x5), x6));
    const float s = expf(x0 - m) + expf(x1 - m) + expf(x2 - m) + expf(x3 - m) +
                    expf(x4 - m) + expf(x5 - m) + expf(x6 - m);
    const int t = targets[row];
    const float xt = (t == 0) ? x0 : (t == 1) ? x1 : (t == 2) ? x2 :
                     (t == 3) ? x3 : (t == 4) ? x4 : (t == 5) ? x5 : x6;
    local += (m - xt) + logf(s);
#pragma unroll
    for (int c = 0; c < NCLS; ++c) cnt[c] += (t == c) ? 1.f : 0.f;
  }

  __shared__ float lds[4];
  const int lane = threadIdx.x & 63, wid = threadIdx.x >> 6;
  float b = wave_reduce(local);
  if (lane == 0) lds[wid] = b;
  __syncthreads();
  if (threadIdx.x == 0) atomicAdd(&ws->ce, (double)(lds[0] + lds[1] + lds[2] + lds[3]));

#pragma unroll
  for (int c = 0; c < NCLS; ++c) {
    __syncthreads();
    float bc = wave_reduce(cnt[c]);
    if (lane == 0) lds[wid] = bc;
    __syncthreads();
    if (threadIdx.x == 0) atomicAdd(&ws->counts[c], lds[0] + lds[1] + lds[2] + lds[3]);
  }
}

// Finalize: WCSS identity + scalar combine. One block, 512 threads (one col each).
__global__ __launch_bounds__(512) void k_fin(const WS* __restrict__ ws,
                                             float* __restrict__ out) {
  const int tid = threadIdx.x;
  float partial = 0.f;
#pragma unroll
  for (int c = 0; c < NCLS; ++c) {
    const float cnt = ws->counts[c];
    const float s = ws->sums[c * DDIM + tid];
    partial += (cnt > 0.f) ? (s * s / cnt) : 0.f;
  }
  __shared__ float lds[8];
  const int lane = tid & 63, wid = tid >> 6;
  float b = wave_reduce(partial);
  if (lane == 0) lds[wid] = b;
  __syncthreads();
  if (tid == 0) {
    float wcss_sub = 0.f;
#pragma unroll
    for (int i = 0; i < 8; ++i) wcss_sub += lds[i];
    const double center = (ws->sumsq - (double)wcss_sub) / (double)BATCH;
    const double ce = ws->ce / (double)BATCH;
    const double l1 = ws->l1 / ((double)BATCH * (double)DDIM);
    const double total = ce + 0.1 * center + 0.01 * l1;
    out[0] = (float)total;
    out[1] = (float)ce;
    out[2] = (float)center;
    out[3] = (float)l1;
  }
}

extern "C" void kernel_launch(void* const* d_in, const int* in_sizes, int n_in,
                              void* d_out, int out_size, void* d_ws, size_t ws_size,
                              hipStream_t stream) {
  const float* outputs  = (const float*)d_in[0];
  const float* features = (const float*)d_in[1];
  const int*   targets  = (const int*)d_in[2];
  const float* aw       = (const float*)d_in[3];
  float* out = (float*)d_out;
  WS* ws = (WS*)d_ws;

  // Workspace accumulators must be zeroed every call (harness does not
  // re-poison between graph replays).
  hipMemsetAsync(d_ws, 0, sizeof(WS), stream);

  k_main<<<GRID_MAIN, 256, 0, stream>>>(features, targets, aw, ws);
  k_ce<<<256, 256, 0, stream>>>(outputs, targets, ws);
  k_fin<<<1, 512, 0, stream>>>(ws, out);
}

// Round 3
// 139.196 us; speedup vs baseline: 1.5727x; 1.5727x over previous
//
#include <hip/hip_runtime.h>

static constexpr int BATCH = 65536;
static constexpr int DDIM  = 512;
static constexpr int NCLS  = 7;
static constexpr int GRID_MAIN = 2048;
static constexpr int RPB = BATCH / GRID_MAIN;   // 32 rows per block
static constexpr int NSLOT = 128;               // contention spreading

struct WS {
  double sumsq_s[NSLOT];
  double l1_s[NSLOT];
  double ce_s[NSLOT];
  double wcss;                     // filled by k_reduce
  float  counts_s[NSLOT][8];       // [slot][class], padded to 8
  float  part[NSLOT][NCLS][DDIM];  // per-slot class sums
};

// Main fused pass: features (class sums via slot-spread atomics, sumsq),
// attention L1, CE over logits, per-class counts.
// Block owns 32 contiguous rows. float4 loads, 4 rows/iter, 64B/thread in flight.
__global__ __launch_bounds__(256, 4) void k_main(const float4* __restrict__ F,
                                                 const float4* __restrict__ A,
                                                 const int* __restrict__ tg,
                                                 const float* __restrict__ outputs,
                                                 WS* __restrict__ ws) {
  const int tid  = threadIdx.x;
  const int bid  = blockIdx.x;
  const int c4   = tid & 127;   // float4 column (0..127)
  const int rsub = tid >> 7;    // 0: rows r, r+2 ; 1: rows r+1, r+3 (wave-uniform)
  const int slot = bid & (NSLOT - 1);
  const int base = bid * RPB;

  float4 acc[NCLS];
#pragma unroll
  for (int c = 0; c < NCLS; ++c) acc[c] = make_float4(0.f, 0.f, 0.f, 0.f);
  float sumsq = 0.f, l1 = 0.f;

#pragma unroll 2
  for (int r = base; r < base + RPB; r += 4) {
    const int4 t4 = *reinterpret_cast<const int4*>(tg + r);
    const size_t i0 = (size_t)(r + rsub) * 128 + c4;
    const float4 f0 = F[i0];
    const float4 f1 = F[i0 + 256];   // row + 2
    const float4 w0 = A[i0];
    const float4 w1 = A[i0 + 256];
    const int ta = rsub ? t4.y : t4.x;
    const int tb = rsub ? t4.w : t4.z;

    sumsq = fmaf(f0.x, f0.x, sumsq); sumsq = fmaf(f0.y, f0.y, sumsq);
    sumsq = fmaf(f0.z, f0.z, sumsq); sumsq = fmaf(f0.w, f0.w, sumsq);
    sumsq = fmaf(f1.x, f1.x, sumsq); sumsq = fmaf(f1.y, f1.y, sumsq);
    sumsq = fmaf(f1.z, f1.z, sumsq); sumsq = fmaf(f1.w, f1.w, sumsq);
    l1 += fabsf(w0.x) + fabsf(w0.y) + fabsf(w0.z) + fabsf(w0.w) +
          fabsf(w1.x) + fabsf(w1.y) + fabsf(w1.z) + fabsf(w1.w);

#pragma unroll
    for (int c = 0; c < NCLS; ++c) {
      acc[c].x += (ta == c) ? f0.x : 0.f;
      acc[c].y += (ta == c) ? f0.y : 0.f;
      acc[c].z += (ta == c) ? f0.z : 0.f;
      acc[c].w += (ta == c) ? f0.w : 0.f;
      acc[c].x += (tb == c) ? f1.x : 0.f;
      acc[c].y += (tb == c) ? f1.y : 0.f;
      acc[c].z += (tb == c) ? f1.z : 0.f;
      acc[c].w += (tb == c) ? f1.w : 0.f;
    }
  }

  // Fold rsub==1 half onto rsub==0 half via LDS (same columns, disjoint rows).
  __shared__ float red[128][NCLS * 4 + 2];
  if (rsub == 1) {
#pragma unroll
    for (int c = 0; c < NCLS; ++c) {
      red[c4][c * 4 + 0] = acc[c].x; red[c4][c * 4 + 1] = acc[c].y;
      red[c4][c * 4 + 2] = acc[c].z; red[c4][c * 4 + 3] = acc[c].w;
    }
    red[c4][28] = sumsq; red[c4][29] = l1;
  }
  __syncthreads();
  if (rsub == 0) {
#pragma unroll
    for (int c = 0; c < NCLS; ++c) {
      acc[c].x += red[c4][c * 4 + 0]; acc[c].y += red[c4][c * 4 + 1];
      acc[c].z += red[c4][c * 4 + 2]; acc[c].w += red[c4][c * 4 + 3];
    }
    sumsq += red[c4][28]; l1 += red[c4][29];

    // Slot-spread atomic merge: 28 atomics/thread over 128 slot copies.
#pragma unroll
    for (int c = 0; c < NCLS; ++c) {
      float* p = &ws->part[slot][c][4 * c4];
      atomicAdd(p + 0, acc[c].x); atomicAdd(p + 1, acc[c].y);
      atomicAdd(p + 2, acc[c].z); atomicAdd(p + 3, acc[c].w);
    }

    // Block-reduce sumsq & l1 over the 128 low threads (2 waves).
    __shared__ float s2[2], s3[2];
    float bs = sumsq, bl = l1;
#pragma unroll
    for (int off = 32; off > 0; off >>= 1) {
      bs += __shfl_down(bs, off);
      bl += __shfl_down(bl, off);
    }
    const int lane = tid & 63, wid = tid >> 6;   // wid 0 or 1 here
    if (lane == 0) { s2[wid] = bs; s3[wid] = bl; }
    __syncthreads();
    if (tid == 0) {
      atomicAdd(&ws->sumsq_s[slot], (double)(s2[0] + s2[1]));
      atomicAdd(&ws->l1_s[slot],    (double)(s3[0] + s3[1]));
    }
  }

  // Per-class counts for this block's 32 rows: threads 0..6, one class each.
  if (tid < NCLS) {
    float cnt = 0.f;
    for (int r = 0; r < RPB; ++r) cnt += (tg[base + r] == tid) ? 1.f : 0.f;
    atomicAdd(&ws->counts_s[slot][tid], cnt);
  }

  // CE over this block's 32 rows: wave 0, lanes 0..31 one row each.
  if (tid < 64) {
    const int lane = tid;
    const int row = base + (lane & 31);
    const float* o = outputs + (size_t)row * NCLS;
    const float x0 = o[0], x1 = o[1], x2 = o[2], x3 = o[3], x4 = o[4], x5 = o[5], x6 = o[6];
    const float m = fmaxf(fmaxf(fmaxf(x0, x1), fmaxf(x2, x3)),
                          fmaxf(fmaxf(x4, x5), x6));
    const float s = expf(x0 - m) + expf(x1 - m) + expf(x2 - m) + expf(x3 - m) +
                    expf(x4 - m) + expf(x5 - m) + expf(x6 - m);
    const int t = tg[row];
    const float xt = (t == 0) ? x0 : (t == 1) ? x1 : (t == 2) ? x2 :
                     (t == 3) ? x3 : (t == 4) ? x4 : (t == 5) ? x5 : x6;
    float v = (lane < 32) ? ((m - xt) + logf(s)) : 0.f;
#pragma unroll
    for (int off = 32; off > 0; off >>= 1) v += __shfl_down(v, off);
    if (lane == 0) atomicAdd(&ws->ce_s[slot], (double)v);
  }
}

// Fold the 128 slot copies of class sums; compute Sum_c ||sums_c||^2 / count_c.
// Grid: 28 blocks x 128 threads. Block = (class c, column quarter q).
__global__ __launch_bounds__(128) void k_reduce(WS* __restrict__ ws) {
  const int c = blockIdx.x >> 2;
  const int q = blockIdx.x & 3;
  const int col = q * 128 + threadIdx.x;

  float s = 0.f;
  for (int sl = 0; sl < NSLOT; ++sl) s += ws->part[sl][c][col];

  float cnt = 0.f;
  for (int sl = 0; sl < NSLOT; ++sl) cnt += ws->counts_s[sl][c];

  float contrib = s * s;
  __shared__ float lds[2];
#pragma unroll
  for (int off = 32; off > 0; off >>= 1) contrib += __shfl_down(contrib, off);
  const int lane = threadIdx.x & 63, wid = threadIdx.x >> 6;
  if (lane == 0) lds[wid] = contrib;
  __syncthreads();
  if (threadIdx.x == 0) {
    const float tot = lds[0] + lds[1];
    atomicAdd(&ws->wcss, (cnt > 0.f) ? (double)(tot / cnt) : 0.0);
  }
}

// Final combine: fold slot scalars, apply WCSS identity, write 4 outputs.
__global__ __launch_bounds__(128) void k_fin(const WS* __restrict__ ws,
                                             float* __restrict__ out) {
  const int tid = threadIdx.x;
  double a = ws->sumsq_s[tid], b = ws->l1_s[tid], d = ws->ce_s[tid];
  __shared__ double la[2], lb[2], ld[2];
#pragma unroll
  for (int off = 32; off > 0; off >>= 1) {
    a += __shfl_down(a, off);
    b += __shfl_down(b, off);
    d += __shfl_down(d, off);
  }
  const int lane = tid & 63, wid = tid >> 6;
  if (lane == 0) { la[wid] = a; lb[wid] = b; ld[wid] = d; }
  __syncthreads();
  if (tid == 0) {
    const double sumsq = la[0] + la[1];
    const double l1s   = lb[0] + lb[1];
    const double ces   = ld[0] + ld[1];
    const double center = (sumsq - ws->wcss) / (double)BATCH;
    const double ce = ces / (double)BATCH;
    const double l1 = l1s / ((double)BATCH * (double)DDIM);
    out[0] = (float)(ce + 0.1 * center + 0.01 * l1);
    out[1] = (float)ce;
    out[2] = (float)center;
    out[3] = (float)l1;
  }
}

extern "C" void kernel_launch(void* const* d_in, const int* in_sizes, int n_in,
                              void* d_out, int out_size, void* d_ws, size_t ws_size,
                              hipStream_t stream) {
  const float*  outputs  = (const float*)d_in[0];
  const float4* features = (const float4*)d_in[1];
  const int*    targets  = (const int*)d_in[2];
  const float4* aw       = (const float4*)d_in[3];
  float* out = (float*)d_out;
  WS* ws = (WS*)d_ws;

  hipMemsetAsync(d_ws, 0, sizeof(WS), stream);

  k_main<<<GRID_MAIN, 256, 0, stream>>>(features, aw, targets, outputs, ws);
  k_reduce<<<NCLS * 4, 128, 0, stream>>>(ws);
  k_fin<<<1, 128, 0, stream>>>(ws, out);
}

// Round 4
// 70.404 us; speedup vs baseline: 3.1095x; 1.9771x over previous
//
#include <hip/hip_runtime.h>

static constexpr int BATCH = 65536;
static constexpr int DDIM  = 512;
static constexpr int NCLS  = 7;
static constexpr int SLICE = NCLS * DDIM;   // 3584 floats per block partial
static constexpr int NSC   = 64;            // scalar slot spread

// Header at d_ws offset 0 (memset to 0 each launch); partials follow at +4096.
struct WS {
  double sumsq_s[NSC];
  double l1_s[NSC];
  double ce_s[NSC];
  double wcss;
  double pad;
  float  counts_s[NSC][8];
};
static_assert(sizeof(WS) <= 4096, "header must fit in 4 KB");

// Fused main pass. Block owns `rpb` contiguous rows.
// - features: per-class sums (registers + LDS fold) -> PLAIN float4 stores to a
//   private workspace slice (no atomics in the hot path), plus sum of squares.
// - attention_weights: L1 accumulation.
// - outputs/targets: cross-entropy + per-class counts (wave-parallel, ballot).
__global__ __launch_bounds__(256, 4) void k_main(const float4* __restrict__ F,
                                                 const float4* __restrict__ A,
                                                 const int* __restrict__ tg,
                                                 const float* __restrict__ outputs,
                                                 float* __restrict__ part,
                                                 WS* __restrict__ ws,
                                                 int rpb) {
  const int tid  = threadIdx.x;
  const int bid  = blockIdx.x;
  const int c4   = tid & 127;   // float4 column (0..127)
  const int rsub = tid >> 7;    // wave-uniform row-phase (0 or 1)
  const int slot = bid & (NSC - 1);
  const int base = bid * rpb;

  float4 acc[NCLS];
#pragma unroll
  for (int c = 0; c < NCLS; ++c) acc[c] = make_float4(0.f, 0.f, 0.f, 0.f);
  float sumsq = 0.f, l1 = 0.f;

#pragma unroll 2
  for (int r = base; r < base + rpb; r += 4) {
    const int4 t4 = *reinterpret_cast<const int4*>(tg + r);
    const size_t i0 = (size_t)(r + rsub) * 128 + c4;
    const float4 f0 = F[i0];
    const float4 f1 = F[i0 + 256];   // row + 2
    const float4 w0 = A[i0];
    const float4 w1 = A[i0 + 256];
    const int ta = rsub ? t4.y : t4.x;
    const int tb = rsub ? t4.w : t4.z;

    sumsq = fmaf(f0.x, f0.x, sumsq); sumsq = fmaf(f0.y, f0.y, sumsq);
    sumsq = fmaf(f0.z, f0.z, sumsq); sumsq = fmaf(f0.w, f0.w, sumsq);
    sumsq = fmaf(f1.x, f1.x, sumsq); sumsq = fmaf(f1.y, f1.y, sumsq);
    sumsq = fmaf(f1.z, f1.z, sumsq); sumsq = fmaf(f1.w, f1.w, sumsq);
    l1 += fabsf(w0.x) + fabsf(w0.y) + fabsf(w0.z) + fabsf(w0.w) +
          fabsf(w1.x) + fabsf(w1.y) + fabsf(w1.z) + fabsf(w1.w);

#pragma unroll
    for (int c = 0; c < NCLS; ++c) {
      acc[c].x += (ta == c) ? f0.x : 0.f;
      acc[c].y += (ta == c) ? f0.y : 0.f;
      acc[c].z += (ta == c) ? f0.z : 0.f;
      acc[c].w += (ta == c) ? f0.w : 0.f;
      acc[c].x += (tb == c) ? f1.x : 0.f;
      acc[c].y += (tb == c) ? f1.y : 0.f;
      acc[c].z += (tb == c) ? f1.z : 0.f;
      acc[c].w += (tb == c) ? f1.w : 0.f;
    }
  }

  // Fold rsub==1 half onto rsub==0 half via LDS.
  __shared__ float red[128][NCLS * 4 + 2];
  if (rsub == 1) {
#pragma unroll
    for (int c = 0; c < NCLS; ++c) {
      red[c4][c * 4 + 0] = acc[c].x; red[c4][c * 4 + 1] = acc[c].y;
      red[c4][c * 4 + 2] = acc[c].z; red[c4][c * 4 + 3] = acc[c].w;
    }
    red[c4][28] = sumsq; red[c4][29] = l1;
  }
  __syncthreads();
  if (rsub == 0) {
#pragma unroll
    for (int c = 0; c < NCLS; ++c) {
      acc[c].x += red[c4][c * 4 + 0]; acc[c].y += red[c4][c * 4 + 1];
      acc[c].z += red[c4][c * 4 + 2]; acc[c].w += red[c4][c * 4 + 3];
    }
    sumsq += red[c4][28]; l1 += red[c4][29];

    // Plain coalesced stores into this block's private slice. No RMW.
    float4* __restrict__ myp = reinterpret_cast<float4*>(part + (size_t)bid * SLICE);
#pragma unroll
    for (int c = 0; c < NCLS; ++c) myp[c * 128 + c4] = acc[c];

    // Block-reduce sumsq & l1 over the 128 low threads (2 waves).
    __shared__ float s2[2], s3[2];
    float bs = sumsq, bl = l1;
#pragma unroll
    for (int off = 32; off > 0; off >>= 1) {
      bs += __shfl_down(bs, off);
      bl += __shfl_down(bl, off);
    }
    const int lane = tid & 63, wid2 = tid >> 6;
    if (lane == 0) { s2[wid2] = bs; s3[wid2] = bl; }
    __syncthreads();
    if (tid == 0) {
      atomicAdd(&ws->sumsq_s[slot], (double)(s2[0] + s2[1]));
      atomicAdd(&ws->l1_s[slot],    (double)(s3[0] + s3[1]));
    }
  }

  // CE + per-class counts over this block's rows, wave-parallel.
  // Wave w handles rows base + k*256 + w*64 + lane  (rpb is a multiple of 64).
  const int lane = tid & 63, wid = tid >> 6;
  if (wid * 64 < rpb) {
    float ce = 0.f;
    float cw[NCLS];
#pragma unroll
    for (int c = 0; c < NCLS; ++c) cw[c] = 0.f;
    for (int r = wid * 64 + lane; r < rpb; r += 256) {
      const int row = base + r;
      const float* o = outputs + (size_t)row * NCLS;
      const float x0 = o[0], x1 = o[1], x2 = o[2], x3 = o[3],
                  x4 = o[4], x5 = o[5], x6 = o[6];
      const float m = fmaxf(fmaxf(fmaxf(x0, x1), fmaxf(x2, x3)),
                            fmaxf(fmaxf(x4, x5), x6));
      const float s = expf(x0 - m) + expf(x1 - m) + expf(x2 - m) + expf(x3 - m) +
                      expf(x4 - m) + expf(x5 - m) + expf(x6 - m);
      const int t = tg[row];
      const float xt = (t == 0) ? x0 : (t == 1) ? x1 : (t == 2) ? x2 :
                       (t == 3) ? x3 : (t == 4) ? x4 : (t == 5) ? x5 : x6;
      ce += (m - xt) + logf(s);
#pragma unroll
      for (int c = 0; c < NCLS; ++c)
        cw[c] += (float)__popcll(__ballot(t == c)) * ((lane == 0) ? 1.f : 0.f);
    }
#pragma unroll
    for (int off = 32; off > 0; off >>= 1) ce += __shfl_down(ce, off);
    if (lane == 0) {
      atomicAdd(&ws->ce_s[slot], (double)ce);
#pragma unroll
      for (int c = 0; c < NCLS; ++c) atomicAdd(&ws->counts_s[slot][c], cw[c]);
    }
  }
}

// Fold nblk private slices; compute Sum_c ||sums_c||^2 / count_c -> ws->wcss.
// Grid: NCLS*16 = 112 blocks x 256 threads. Block = (class c, 32-col group).
__global__ __launch_bounds__(256) void k_reduce(const float* __restrict__ part,
                                                WS* __restrict__ ws, int nblk) {
  const int c  = blockIdx.x >> 4;
  const int cg = blockIdx.x & 15;
  const int t  = threadIdx.x;
  const int col = cg * 32 + (t & 31);
  const int sl0 = t >> 5;   // 0..7

  float s = 0.f;
#pragma unroll 4
  for (int sl = sl0; sl < nblk; sl += 8)
    s += part[(size_t)sl * SLICE + c * DDIM + col];

  __shared__ float red[8][33];
  red[sl0][t & 31] = s;

  __shared__ float scnt;
  if (t < 64) {
    float cv = ws->counts_s[t][c];
#pragma unroll
    for (int off = 32; off > 0; off >>= 1) cv += __shfl_down(cv, off);
    if (t == 0) scnt = cv;
  }
  __syncthreads();

  if (t < 32) {
    float S = 0.f;
#pragma unroll
    for (int i = 0; i < 8; ++i) S += red[i][t];
    float q = S * S;
#pragma unroll
    for (int off = 16; off > 0; off >>= 1) q += __shfl_down(q, off);
    if (t == 0 && scnt > 0.f) atomicAdd(&ws->wcss, (double)(q / scnt));
  }
}

// Final combine: fold scalar slots, WCSS identity, write the 4 outputs.
__global__ __launch_bounds__(64) void k_fin(const WS* __restrict__ ws,
                                            float* __restrict__ out) {
  const int t = threadIdx.x;
  double a = ws->sumsq_s[t], b = ws->l1_s[t], d = ws->ce_s[t];
#pragma unroll
  for (int off = 32; off > 0; off >>= 1) {
    a += __shfl_down(a, off);
    b += __shfl_down(b, off);
    d += __shfl_down(d, off);
  }
  if (t == 0) {
    const double center = (a - ws->wcss) / (double)BATCH;
    const double ce = d / (double)BATCH;
    const double l1 = b / ((double)BATCH * (double)DDIM);
    out[0] = (float)(ce + 0.1 * center + 0.01 * l1);
    out[1] = (float)ce;
    out[2] = (float)center;
    out[3] = (float)l1;
  }
}

extern "C" void kernel_launch(void* const* d_in, const int* in_sizes, int n_in,
                              void* d_out, int out_size, void* d_ws, size_t ws_size,
                              hipStream_t stream) {
  const float*  outputs  = (const float*)d_in[0];
  const float4* features = (const float4*)d_in[1];
  const int*    targets  = (const int*)d_in[2];
  const float4* aw       = (const float4*)d_in[3];
  float* out = (float*)d_out;
  WS* ws = (WS*)d_ws;
  float* part = (float*)((char*)d_ws + 4096);

  // Pick the largest block count whose private partials fit the workspace.
  // (128 -> 1.84 MB, proven to fit in earlier rounds.)
  const size_t avail = (ws_size > 4096) ? ws_size - 4096 : 0;
  int nblk = 128;
  if (avail >= (size_t)1024 * SLICE * 4) nblk = 1024;
  else if (avail >= (size_t)512 * SLICE * 4) nblk = 512;
  else if (avail >= (size_t)256 * SLICE * 4) nblk = 256;
  const int rpb = BATCH / nblk;

  hipMemsetAsync(d_ws, 0, 4096, stream);

  k_main<<<nblk, 256, 0, stream>>>(features, aw, targets, outputs, part, ws, rpb);
  k_reduce<<<NCLS * 16, 256, 0, stream>>>(part, ws, nblk);
  k_fin<<<1, 64, 0, stream>>>(ws, out);
}